// Round 4
// baseline (6739.344 us; speedup 1.0000x reference)
//
#include <hip/hip_runtime.h>

// RecurrentGaussianActor: fused LSTM(64->256) + Linear+ReLU(256) + 2 heads(16).
// R4: 256 WGs x 256 threads (1 WG/CU, 4 waves). Thread j owns unit j: all four
// gate rows (j, j+256, j+512, j+768) over the FULL K=256. Register budget at
// 1 wave/SIMD = 512 combined VGPR+AGPR per thread: W_hh pairs [32,128) live in
// 96 h8 = 384 regs (provable fit; R2/R3 spilled at the 256-reg budget and
// streamed weights from L2 scratch every step - the 4.45 ms plateau).
// Pairs [0,32) in LDS (128 KB, [p4][row] b128 conflict-free). One barrier per
// step via double-buffered h. No partial exchange: owner thread does full dot
// + elementwise. Chunk phases (xg, layer2, heads) stream small weights from L2.

#define NB 256
#define NT 1000
#define NF 64
#define NH 256
#define NG 1024
#define NA 16
#define NTHREADS 256
#define CHUNK 8
#define NCHUNK (NT / CHUNK)

typedef _Float16 h2 __attribute__((ext_vector_type(2)));
typedef _Float16 h4 __attribute__((ext_vector_type(4)));
typedef _Float16 h8 __attribute__((ext_vector_type(8)));
typedef float f4 __attribute__((ext_vector_type(4)));

__device__ __forceinline__ float fdot2(h2 a, h2 b, float c) {
  return __builtin_amdgcn_fdot2(a, b, c, false);
}
__device__ __forceinline__ float fexp2(float x) { return __builtin_amdgcn_exp2f(x); }
__device__ __forceinline__ float frcp(float x) { return __builtin_amdgcn_rcpf(x); }
__device__ __forceinline__ float sigmoidf_(float x) {
  return frcp(1.f + fexp2(-1.4426950408889634f * x));
}
__device__ __forceinline__ float tanhfast(float x) {
  float a = fabsf(x);
  float e = fexp2(-2.8853900817779268f * a);
  float r = (1.f - e) * frcp(1.f + e);
  return __builtin_copysignf(r, x);
}
__device__ __forceinline__ float dot8(h8 x, h8 w, float acc) {
  acc = fdot2(__builtin_shufflevector(x, x, 0, 1), __builtin_shufflevector(w, w, 0, 1), acc);
  acc = fdot2(__builtin_shufflevector(x, x, 2, 3), __builtin_shufflevector(w, w, 2, 3), acc);
  acc = fdot2(__builtin_shufflevector(x, x, 4, 5), __builtin_shufflevector(w, w, 4, 5), acc);
  acc = fdot2(__builtin_shufflevector(x, x, 6, 7), __builtin_shufflevector(w, w, 6, 7), acc);
  return acc;
}

// ---- prep: convert/pack weights to f16 pairs in workspace ----
__global__ void prep_kernel(const float* __restrict__ Wih, const float* __restrict__ Whh,
                            const float* __restrict__ bih, const float* __restrict__ bhh,
                            const float* __restrict__ W2, const float* __restrict__ Wm,
                            const float* __restrict__ Ws,
                            h2* __restrict__ whh, h2* __restrict__ wih,
                            h2* __restrict__ w2w, h2* __restrict__ wmh,
                            float* __restrict__ bg) {
  int i = blockIdx.x * 256 + threadIdx.x;
  if (i < 1024 * 128) {  // W_hh [1024][256] -> [1024][128] pairs
    int j = i >> 7, p = i & 127;
    whh[i] = h2{(_Float16)Whh[j * 256 + 2 * p], (_Float16)Whh[j * 256 + 2 * p + 1]};
  }
  if (i < 1024 * 32) {   // W_ih [1024][64] -> [1024][32] pairs
    int j = i >> 5, p = i & 31;
    wih[i] = h2{(_Float16)Wih[j * 64 + 2 * p], (_Float16)Wih[j * 64 + 2 * p + 1]};
  }
  if (i < 256 * 128) {   // W2 [256][256] -> [256][128] pairs
    int j = i >> 7, p = i & 127;
    w2w[i] = h2{(_Float16)W2[j * 256 + 2 * p], (_Float16)W2[j * 256 + 2 * p + 1]};
  }
  if (i < 32 * 128) {    // Wm rows 0..15, Ws rows 16..31
    int j = i >> 7, p = i & 127;
    float v0, v1;
    if (j < 16) { v0 = Wm[j * 256 + 2 * p]; v1 = Wm[j * 256 + 2 * p + 1]; }
    else        { v0 = Ws[(j - 16) * 256 + 2 * p]; v1 = Ws[(j - 16) * 256 + 2 * p + 1]; }
    wmh[i] = h2{(_Float16)v0, (_Float16)v1};
  }
  if (i < 1024) bg[i] = bih[i] + bhh[i];
}

// ---- main fused persistent kernel: 1 WG per batch row, 256 threads ----
__global__ __launch_bounds__(NTHREADS, 1) void actor_kernel(
    const float* __restrict__ obs,
    const h2* __restrict__ whh, const h2* __restrict__ wih,
    const h2* __restrict__ w2w, const h2* __restrict__ wmh,
    const float* __restrict__ bg, const float* __restrict__ b2,
    const float* __restrict__ bm, const float* __restrict__ bs,
    float* __restrict__ out) {
  __shared__ __align__(16) h8 whh_l[8 * 1024];          // 131072 B  pairs [0,32), [p4][row]
  __shared__ __align__(16) _Float16 xg_l[CHUNK * NG];   // 16384 B   [t][unit*4+gate]
  __shared__ __align__(16) h8 hbuf[2][NH / 8];          // 1024 B    double-buffered h (f16)
  __shared__ __align__(16) _Float16 hch[CHUNK * NH];    // 4096 B    h history
  __shared__ __align__(16) h2 xbuf[CHUNK * NF / 2];     // 1024 B    obs chunk
  __shared__ __align__(16) _Float16 x2b[CHUNK * NH];    // 4096 B    layer2 out
  // total 157696 B <= 163840

  const int tid = threadIdx.x;
  const int b = blockIdx.x;
  const int j = tid;  // unit index; gate rows j + 256*g

  // ---- register-resident W_hh: rows j+256g, h8-groups [8, 32) (pairs 32..127) ----
  h8 wreg[96];  // [g*24 + m] -> 384 regs
  {
    const volatile h8* vw = (const volatile h8*)whh;  // row stride = 32 h8
#pragma unroll
    for (int g = 0; g < 4; g++)
#pragma unroll
      for (int m = 0; m < 24; m++)
        wreg[g * 24 + m] = vw[(g * 256 + j) * 32 + 8 + m];
  }
  // ---- LDS-resident W_hh: h8-groups [0, 8) (pairs 0..31) of every row ----
  {
    const h8* whh8 = (const h8*)whh;
    for (int k = tid; k < 8 * 1024; k += NTHREADS) {
      int q = k >> 10, row = k & 1023;
      whh_l[q * 1024 + row] = whh8[row * 32 + q];
    }
  }
  if (tid < 32) hbuf[0][tid] = h8{0, 0, 0, 0, 0, 0, 0, 0};
  float c_state = 0.f;
  float bg4[4];
#pragma unroll
  for (int g = 0; g < 4; g++) bg4[g] = bg[g * 256 + j];
  const float b2v = b2[j];
  const int oh = j & 31;
  const float hbv = (oh < NA) ? bm[oh] : bs[oh - NA];
  __syncthreads();

  const float* obs_b = obs + (size_t)b * NT * NF;
  float* out_means = out;
  float* out_stds = out + (size_t)NB * NT * NA;

  for (int ch = 0; ch < NCHUNK; ++ch) {
    const int t0 = ch * CHUNK;

    // ---- stage obs chunk -> f16 pairs in LDS ----
    if (tid < 128) {
      int t = tid >> 4, fq = tid & 15;
      f4 v = *(const f4*)(obs_b + (size_t)(t0 + t) * NF + fq * 4);
      xbuf[t * 32 + fq * 2] = h2{(_Float16)v[0], (_Float16)v[1]};
      xbuf[t * 32 + fq * 2 + 1] = h2{(_Float16)v[2], (_Float16)v[3]};
    }
    __syncthreads();

    // ---- xg = obs @ W_ih^T + (b_ih+b_hh); store [t][j*4+g] ----
#pragma unroll
    for (int g = 0; g < 4; g++) {
      const h8* wrow = (const h8*)wih + (g * 256 + j) * 8;
      h8 w[8];
#pragma unroll
      for (int q = 0; q < 8; q++) w[q] = wrow[q];
      float acc[CHUNK];
#pragma unroll
      for (int t = 0; t < CHUNK; t++) acc[t] = bg4[g];
#pragma unroll
      for (int t = 0; t < CHUNK; t++)
#pragma unroll
        for (int q = 0; q < 8; q++)
          acc[t] = dot8(*(const h8*)&xbuf[t * 32 + q * 4], w[q], acc[t]);
#pragma unroll
      for (int t = 0; t < CHUNK; t++) xg_l[t * NG + j * 4 + g] = (_Float16)acc[t];
    }
    __syncthreads();

    // ---- 8 recurrent LSTM steps, ONE barrier each ----
    for (int t = 0; t < CHUNK; t++) {
      const int st = t0 + t;
      const int rb = st & 1;
      float a0 = 0.f, a1 = 0.f, a2 = 0.f, a3 = 0.f;
      // LDS weight part: pairs [0,32)
#pragma unroll
      for (int q = 0; q < 8; q++) {
        h8 hv = hbuf[rb][q];  // wave-uniform broadcast
        const h8* wl = &whh_l[q * 1024 + j];
        a0 = dot8(hv, wl[0], a0);
        a1 = dot8(hv, wl[256], a1);
        a2 = dot8(hv, wl[512], a2);
        a3 = dot8(hv, wl[768], a3);
      }
      // register part: pairs [32,128)
#pragma unroll
      for (int m = 0; m < 24; m++) {
        h8 hv = hbuf[rb][8 + m];
        a0 = dot8(hv, wreg[m], a0);
        a1 = dot8(hv, wreg[24 + m], a1);
        a2 = dot8(hv, wreg[48 + m], a2);
        a3 = dot8(hv, wreg[72 + m], a3);
      }
      h4 xg4 = *(const h4*)&xg_l[t * NG + j * 4];
      float gi = sigmoidf_(a0 + (float)xg4[0]);
      float gf = sigmoidf_(a1 + (float)xg4[1]);
      float gg = tanhfast(a2 + (float)xg4[2]);
      float go = sigmoidf_(a3 + (float)xg4[3]);
      c_state = gf * c_state + gi * gg;
      float hval = go * tanhfast(c_state);
      _Float16 hh = (_Float16)hval;
      ((_Float16*)hbuf[rb ^ 1])[j] = hh;  // next step's h
      hch[t * NH + j] = hh;
      __syncthreads();
    }

    // ---- layer2: x2 = relu(h @ W2^T + b2) ----
    {
      float acc[CHUNK];
#pragma unroll
      for (int t = 0; t < CHUNK; t++) acc[t] = b2v;
      const h8* wrow = (const h8*)w2w + j * 32;
#pragma unroll 2
      for (int c4 = 0; c4 < 8; c4++) {
        h8 w[4];
#pragma unroll
        for (int q = 0; q < 4; q++) w[q] = wrow[c4 * 4 + q];
#pragma unroll
        for (int t = 0; t < CHUNK; t++)
#pragma unroll
          for (int q = 0; q < 4; q++)
            acc[t] = dot8(*(const h8*)&hch[t * NH + c4 * 32 + q * 8], w[q], acc[t]);
      }
#pragma unroll
      for (int t = 0; t < CHUNK; t++)
        x2b[t * NH + j] = (_Float16)fmaxf(acc[t], 0.f);
    }
    __syncthreads();

    // ---- heads: 32 outputs x 8 timesteps ----
    {
      const int tt = j >> 5;
      const h8* wrow = (const h8*)wmh + oh * 32;
      float acc = 0.f;
#pragma unroll 4
      for (int c = 0; c < 32; c++)
        acc = dot8(*(const h8*)&x2b[tt * NH + c * 8], wrow[c], acc);
      acc += hbv;
      const size_t idx = ((size_t)b * NT + (t0 + tt)) * NA + (oh & 15);
      if (oh < NA) {
        out_means[idx] = acc;
      } else {
        float ls = fminf(fmaxf(acc, -20.f), 2.f);
        out_stds[idx] = fexp2(1.4426950408889634f * ls);
      }
    }
    // no trailing barrier: next chunk's writes (xbuf, xg_l, hch, x2b) are all
    // separated from these reads by the staging/xg/step barriers above.
  }
}

extern "C" void kernel_launch(void* const* d_in, const int* in_sizes, int n_in,
                              void* d_out, int out_size, void* d_ws, size_t ws_size,
                              hipStream_t stream) {
  const float* obs = (const float*)d_in[0];
  const float* Wih = (const float*)d_in[1];
  const float* Whh = (const float*)d_in[2];
  const float* bih = (const float*)d_in[3];
  const float* bhh = (const float*)d_in[4];
  const float* W2 = (const float*)d_in[5];
  const float* b2 = (const float*)d_in[6];
  const float* Wm = (const float*)d_in[7];
  const float* bm = (const float*)d_in[8];
  const float* Ws = (const float*)d_in[9];
  const float* bs = (const float*)d_in[10];

  char* ws = (char*)d_ws;
  h2* whh = (h2*)(ws + 0);            // 512 KB
  h2* wih = (h2*)(ws + 524288);       // 128 KB
  h2* w2w = (h2*)(ws + 655360);       // 128 KB
  h2* wmh = (h2*)(ws + 786432);       // 16 KB
  float* bg = (float*)(ws + 802816);  // 4 KB

  prep_kernel<<<512, 256, 0, stream>>>(Wih, Whh, bih, bhh, W2, Wm, Ws,
                                       whh, wih, w2w, wmh, bg);
  actor_kernel<<<NB, NTHREADS, 0, stream>>>(obs, whh, wih, w2w, wmh, bg, b2, bm,
                                            bs, (float*)d_out);
}

// Round 6
// 6348.885 us; speedup vs baseline: 1.0615x; 1.0615x over previous
//
#include <hip/hip_runtime.h>

// RecurrentGaussianActor: fused LSTM(64->256) + Linear+ReLU(256) + 2 heads(16).
// R6 (= R5 + compile fix): 256 WGs x 256 threads. Thread j owns unit j (gate
// rows j+256g, full K). W_hh residency, explicitly split (32 h8-groups/row):
//   q [0,6):  LDS, 96 KB, [q][row] b128 stride-1 (conflict-free)
//   q [6,16): arch VGPRs, 40 h8 = 160 regs (volatile loads, R2-proven resident)
//   q [16,32): 256 AGPRs, pinned via inline-asm "a" constraints
//              (v_accvgpr_write once; volatile v_accvgpr_read in-loop).
// Arch pressure ~220/256 leaves ~35 regs so the compiler can pipeline LDS
// loads (R2's 4.45 ms = latency serialization at 252/256 arch regs).
// One barrier per step (double-buffered h). Chunk phases stream small weights.

#define NB 256
#define NT 1000
#define NF 64
#define NH 256
#define NG 1024
#define NA 16
#define NTHREADS 256
#define CHUNK 8
#define NCHUNK (NT / CHUNK)
#define QL 6   // h8-groups per row in LDS
#define QA 10  // h8-groups per row in arch VGPRs

typedef _Float16 h2 __attribute__((ext_vector_type(2)));
typedef _Float16 h4 __attribute__((ext_vector_type(4)));
typedef _Float16 h8 __attribute__((ext_vector_type(8)));
typedef float f4 __attribute__((ext_vector_type(4)));

#define AGW(a, v) asm volatile("v_accvgpr_write_b32 %0, %1" : "=a"(a) : "v"(v))
#define AGR(v, a) asm volatile("v_accvgpr_read_b32 %0, %1" : "=v"(v) : "a"(a))

__device__ __forceinline__ float fdot2(h2 a, h2 b, float c) {
  return __builtin_amdgcn_fdot2(a, b, c, false);
}
__device__ __forceinline__ float fexp2(float x) { return __builtin_amdgcn_exp2f(x); }
__device__ __forceinline__ float frcp(float x) { return __builtin_amdgcn_rcpf(x); }
__device__ __forceinline__ float sigmoidf_(float x) {
  return frcp(1.f + fexp2(-1.4426950408889634f * x));
}
__device__ __forceinline__ float tanhfast(float x) {
  float a = fabsf(x);
  float e = fexp2(-2.8853900817779268f * a);
  float r = (1.f - e) * frcp(1.f + e);
  return __builtin_copysignf(r, x);
}
__device__ __forceinline__ float dot8(h8 x, h8 w, float acc) {
  acc = fdot2(__builtin_shufflevector(x, x, 0, 1), __builtin_shufflevector(w, w, 0, 1), acc);
  acc = fdot2(__builtin_shufflevector(x, x, 2, 3), __builtin_shufflevector(w, w, 2, 3), acc);
  acc = fdot2(__builtin_shufflevector(x, x, 4, 5), __builtin_shufflevector(w, w, 4, 5), acc);
  acc = fdot2(__builtin_shufflevector(x, x, 6, 7), __builtin_shufflevector(w, w, 6, 7), acc);
  return acc;
}

// ---- prep: convert/pack weights to f16 pairs in workspace ----
__global__ void prep_kernel(const float* __restrict__ Wih, const float* __restrict__ Whh,
                            const float* __restrict__ bih, const float* __restrict__ bhh,
                            const float* __restrict__ W2, const float* __restrict__ Wm,
                            const float* __restrict__ Ws,
                            h2* __restrict__ whh, h2* __restrict__ wih,
                            h2* __restrict__ w2w, h2* __restrict__ wmh,
                            float* __restrict__ bg) {
  int i = blockIdx.x * 256 + threadIdx.x;
  if (i < 1024 * 128) {  // W_hh [1024][256] -> [1024][128] pairs
    int j = i >> 7, p = i & 127;
    whh[i] = h2{(_Float16)Whh[j * 256 + 2 * p], (_Float16)Whh[j * 256 + 2 * p + 1]};
  }
  if (i < 1024 * 32) {   // W_ih [1024][64] -> [1024][32] pairs
    int j = i >> 5, p = i & 31;
    wih[i] = h2{(_Float16)Wih[j * 64 + 2 * p], (_Float16)Wih[j * 64 + 2 * p + 1]};
  }
  if (i < 256 * 128) {   // W2 [256][256] -> [256][128] pairs
    int j = i >> 7, p = i & 127;
    w2w[i] = h2{(_Float16)W2[j * 256 + 2 * p], (_Float16)W2[j * 256 + 2 * p + 1]};
  }
  if (i < 32 * 128) {    // Wm rows 0..15, Ws rows 16..31
    int j = i >> 7, p = i & 127;
    float v0, v1;
    if (j < 16) { v0 = Wm[j * 256 + 2 * p]; v1 = Wm[j * 256 + 2 * p + 1]; }
    else        { v0 = Ws[(j - 16) * 256 + 2 * p]; v1 = Ws[(j - 16) * 256 + 2 * p + 1]; }
    wmh[i] = h2{(_Float16)v0, (_Float16)v1};
  }
  if (i < 1024) bg[i] = bih[i] + bhh[i];
}

// ---- main fused persistent kernel: 1 WG per batch row, 256 threads ----
__global__ __launch_bounds__(NTHREADS, 1) void actor_kernel(
    const float* __restrict__ obs,
    const h2* __restrict__ whh, const h2* __restrict__ wih,
    const h2* __restrict__ w2w, const h2* __restrict__ wmh,
    const float* __restrict__ bg, const float* __restrict__ b2,
    const float* __restrict__ bm, const float* __restrict__ bs,
    float* __restrict__ out) {
  __shared__ __align__(16) h8 whh_l[QL * 1024];         // 98304 B  [q][row]
  __shared__ __align__(16) _Float16 xg_l[CHUNK * NG];   // 16384 B  [t][unit*4+gate]
  __shared__ __align__(16) h8 hbuf[2][NH / 8];          // 1024 B   double-buffered h
  __shared__ __align__(16) _Float16 hch[CHUNK * NH];    // 4096 B   h history
  __shared__ __align__(16) h2 xbuf[CHUNK * NF / 2];     // 1024 B   obs chunk
  __shared__ __align__(16) _Float16 x2b[CHUNK * NH];    // 4096 B   layer2 out
  // total 124928 B <= 163840

  const int tid = threadIdx.x;
  const int b = blockIdx.x;
  const int j = tid;  // unit index; gate rows j + 256*g

  // ---- AGPR-resident W_hh: q-groups [16,32), pinned via asm "a" class ----
  float ag[4][16][4];  // 256 accum dwords (each = one h2 pair, bit-pattern)
  {
    const volatile f4* vwf = (const volatile f4*)whh;  // h8 bit-view, row stride 32
#pragma unroll
    for (int r = 0; r < 4; r++) {
      const int row = r * 256 + j;
#pragma unroll
      for (int q = 0; q < 16; q++) {
        f4 w = vwf[row * 32 + 16 + q];
        AGW(ag[r][q][0], w[0]);
        AGW(ag[r][q][1], w[1]);
        AGW(ag[r][q][2], w[2]);
        AGW(ag[r][q][3], w[3]);
      }
    }
  }
  // ---- arch-VGPR-resident W_hh: q-groups [6,16) ----
  h8 wa[4][QA];  // 160 regs
  {
    const volatile h8* vw8 = (const volatile h8*)whh;
#pragma unroll
    for (int r = 0; r < 4; r++)
#pragma unroll
      for (int m = 0; m < QA; m++)
        wa[r][m] = vw8[(r * 256 + j) * 32 + QL + m];
  }
  // ---- LDS-resident W_hh: q-groups [0,6) of every row ----
  {
    const h8* whh8 = (const h8*)whh;
    for (int k = tid; k < QL * 1024; k += NTHREADS) {
      int q = k >> 10, row = k & 1023;
      whh_l[q * 1024 + row] = whh8[row * 32 + q];
    }
  }
  if (tid < 32) hbuf[0][tid] = h8{0, 0, 0, 0, 0, 0, 0, 0};
  float c_state = 0.f;
  float bg4[4];
#pragma unroll
  for (int g = 0; g < 4; g++) bg4[g] = bg[g * 256 + j];
  const float b2v = b2[j];
  const int oh = j & 31;
  const float hbv = (oh < NA) ? bm[oh] : bs[oh - NA];
  __syncthreads();

  const float* obs_b = obs + (size_t)b * NT * NF;
  float* out_means = out;
  float* out_stds = out + (size_t)NB * NT * NA;

  for (int ch = 0; ch < NCHUNK; ++ch) {
    const int t0 = ch * CHUNK;

    // ---- stage obs chunk -> f16 pairs in LDS ----
    if (tid < 128) {
      int t = tid >> 4, fq = tid & 15;
      f4 v = *(const f4*)(obs_b + (size_t)(t0 + t) * NF + fq * 4);
      xbuf[t * 32 + fq * 2] = h2{(_Float16)v[0], (_Float16)v[1]};
      xbuf[t * 32 + fq * 2 + 1] = h2{(_Float16)v[2], (_Float16)v[3]};
    }
    __syncthreads();

    // ---- xg = obs @ W_ih^T + (b_ih+b_hh); store [t][j*4+g] ----
#pragma unroll
    for (int g = 0; g < 4; g++) {
      const h8* wrow = (const h8*)wih + (g * 256 + j) * 8;
      h8 w[8];
#pragma unroll
      for (int q = 0; q < 8; q++) w[q] = wrow[q];
      float acc[CHUNK];
#pragma unroll
      for (int t = 0; t < CHUNK; t++) acc[t] = bg4[g];
#pragma unroll
      for (int t = 0; t < CHUNK; t++)
#pragma unroll
        for (int q = 0; q < 8; q++)
          acc[t] = dot8(*(const h8*)&xbuf[t * 32 + q * 4], w[q], acc[t]);
#pragma unroll
      for (int t = 0; t < CHUNK; t++) xg_l[t * NG + j * 4 + g] = (_Float16)acc[t];
    }
    __syncthreads();

    // ---- 8 recurrent LSTM steps, ONE barrier each ----
    for (int t = 0; t < CHUNK; t++) {
      const int st = t0 + t;
      const int rb = st & 1;
      const h8* hsrc = hbuf[rb];
      float a0 = 0.f, a1 = 0.f, a2 = 0.f, a3 = 0.f;
      // LDS weight part: q [0,6)
#pragma unroll
      for (int q = 0; q < QL; q++) {
        h8 hv = hsrc[q];  // wave-uniform broadcast
        const h8* wl = &whh_l[q * 1024 + j];
        a0 = dot8(hv, wl[0], a0);
        a1 = dot8(hv, wl[256], a1);
        a2 = dot8(hv, wl[512], a2);
        a3 = dot8(hv, wl[768], a3);
      }
      // arch-VGPR part: q [6,16)
#pragma unroll
      for (int m = 0; m < QA; m++) {
        h8 hv = hsrc[QL + m];
        a0 = dot8(hv, wa[0][m], a0);
        a1 = dot8(hv, wa[1][m], a1);
        a2 = dot8(hv, wa[2][m], a2);
        a3 = dot8(hv, wa[3][m], a3);
      }
      // AGPR part: q [16,32)
#pragma unroll
      for (int q = 0; q < 16; q++) {
        h8 hv = hsrc[16 + q];
        f4 hf = __builtin_bit_cast(f4, hv);
#pragma unroll
        for (int d = 0; d < 4; d++) {
          h2 hp = __builtin_bit_cast(h2, hf[d]);
          float w0, w1, w2, w3;
          AGR(w0, ag[0][q][d]);
          AGR(w1, ag[1][q][d]);
          AGR(w2, ag[2][q][d]);
          AGR(w3, ag[3][q][d]);
          a0 = fdot2(hp, __builtin_bit_cast(h2, w0), a0);
          a1 = fdot2(hp, __builtin_bit_cast(h2, w1), a1);
          a2 = fdot2(hp, __builtin_bit_cast(h2, w2), a2);
          a3 = fdot2(hp, __builtin_bit_cast(h2, w3), a3);
        }
      }
      h4 xg4 = *(const h4*)&xg_l[t * NG + j * 4];
      float gi = sigmoidf_(a0 + (float)xg4[0]);
      float gf = sigmoidf_(a1 + (float)xg4[1]);
      float gg = tanhfast(a2 + (float)xg4[2]);
      float go = sigmoidf_(a3 + (float)xg4[3]);
      c_state = gf * c_state + gi * gg;
      float hval = go * tanhfast(c_state);
      _Float16 hh = (_Float16)hval;
      ((_Float16*)hbuf[rb ^ 1])[j] = hh;  // next step's h
      hch[t * NH + j] = hh;
      __syncthreads();
    }

    // ---- layer2: x2 = relu(h @ W2^T + b2) ----
    {
      float acc[CHUNK];
#pragma unroll
      for (int t = 0; t < CHUNK; t++) acc[t] = b2v;
      const h8* wrow = (const h8*)w2w + j * 32;
#pragma unroll 2
      for (int c4 = 0; c4 < 8; c4++) {
        h8 w[4];
#pragma unroll
        for (int q = 0; q < 4; q++) w[q] = wrow[c4 * 4 + q];
#pragma unroll
        for (int t = 0; t < CHUNK; t++)
#pragma unroll
          for (int q = 0; q < 4; q++)
            acc[t] = dot8(*(const h8*)&hch[t * NH + c4 * 32 + q * 8], w[q], acc[t]);
      }
#pragma unroll
      for (int t = 0; t < CHUNK; t++)
        x2b[t * NH + j] = (_Float16)fmaxf(acc[t], 0.f);
    }
    __syncthreads();

    // ---- heads: 32 outputs x 8 timesteps ----
    {
      const int tt = j >> 5;
      const h8* wrow = (const h8*)wmh + oh * 32;
      float acc = 0.f;
#pragma unroll 4
      for (int c = 0; c < 32; c++)
        acc = dot8(*(const h8*)&x2b[tt * NH + c * 8], wrow[c], acc);
      acc += hbv;
      const size_t idx = ((size_t)b * NT + (t0 + tt)) * NA + (oh & 15);
      if (oh < NA) {
        out_means[idx] = acc;
      } else {
        float ls = fminf(fmaxf(acc, -20.f), 2.f);
        out_stds[idx] = fexp2(1.4426950408889634f * ls);
      }
    }
    // no trailing barrier: next chunk's writes (xbuf, xg_l, hch, x2b) are all
    // separated from these reads by the staging/xg/step barriers above.
  }
}

extern "C" void kernel_launch(void* const* d_in, const int* in_sizes, int n_in,
                              void* d_out, int out_size, void* d_ws, size_t ws_size,
                              hipStream_t stream) {
  const float* obs = (const float*)d_in[0];
  const float* Wih = (const float*)d_in[1];
  const float* Whh = (const float*)d_in[2];
  const float* bih = (const float*)d_in[3];
  const float* bhh = (const float*)d_in[4];
  const float* W2 = (const float*)d_in[5];
  const float* b2 = (const float*)d_in[6];
  const float* Wm = (const float*)d_in[7];
  const float* bm = (const float*)d_in[8];
  const float* Ws = (const float*)d_in[9];
  const float* bs = (const float*)d_in[10];

  char* ws = (char*)d_ws;
  h2* whh = (h2*)(ws + 0);            // 512 KB
  h2* wih = (h2*)(ws + 524288);       // 128 KB
  h2* w2w = (h2*)(ws + 655360);       // 128 KB
  h2* wmh = (h2*)(ws + 786432);       // 16 KB
  float* bg = (float*)(ws + 802816);  // 4 KB

  prep_kernel<<<512, 256, 0, stream>>>(Wih, Whh, bih, bhh, W2, Wm, Ws,
                                       whh, wih, w2w, wmh, bg);
  actor_kernel<<<NB, NTHREADS, 0, stream>>>(obs, whh, wih, w2w, wmh, bg, b2, bm,
                                            bs, (float*)d_out);
}